// Round 1
// baseline (107.730 us; speedup 1.0000x reference)
//
#include <hip/hip_runtime.h>
#include <hip/hip_bf16.h>
#include <stdint.h>

typedef float f32x4 __attribute__((ext_vector_type(4)));
typedef float f32x4v __attribute__((ext_vector_type(4)));
typedef short short8 __attribute__((ext_vector_type(8)));
typedef unsigned short u16;
typedef unsigned short u16x8 __attribute__((ext_vector_type(8)));
typedef unsigned short u16x4 __attribute__((ext_vector_type(4)));

#define MFMA16x16x32 __builtin_amdgcn_mfma_f32_16x16x32_bf16

__device__ __forceinline__ u16 f2bf(float f) {
    unsigned int u = __builtin_bit_cast(unsigned int, f);
    u += 0x7fffu + ((u >> 16) & 1u);
    return (u16)(u >> 16);
}

// ---------------------------------------------------------------------------
// Kernel 0: W [1024,128] f32  ->  WT [3][128][1024] bf16 (transposed)
// ---------------------------------------------------------------------------
__global__ void k_transpose_w(const float* __restrict__ Wq, const float* __restrict__ Wk,
                              const float* __restrict__ Wv, u16* __restrict__ WT) {
    int tid = blockIdx.x * 256 + threadIdx.x;  // 0..49151
    int w   = tid >> 14;                       // 0..2
    int rem = tid & 16383;
    int n   = rem >> 7;                        // 0..127
    int kc  = rem & 127;                       // 0..127, 8 k-values each
    const float* W = (w == 0) ? Wq : ((w == 1) ? Wk : Wv);
    u16x8 v;
#pragma unroll
    for (int j = 0; j < 8; ++j)
        v[j] = f2bf(W[(size_t)(kc * 8 + j) * 128 + n]);
    *(u16x8*)(&WT[((size_t)w << 17) + (size_t)n * 1024 + kc * 8]) = v;
}

// ---------------------------------------------------------------------------
// Kernel 1: QKV projection GEMM.  x[16384,1024] f32 @ WT^T -> q/k bf16 [16384,128],
//           v stored transposed vT[8][128][2048] bf16.
// Tile: BM=128, BN=128(=HS), BK=64.  4 waves (2x2), each 64x64 via 4x4 16x16x32 frags.
// LDS XOR-swizzle: 16B-block index ^= (row&7)  (kills stride-128B bank conflicts).
// ---------------------------------------------------------------------------
__global__ __launch_bounds__(256) void k_qkv_gemm(
    const float* __restrict__ x, const u16* __restrict__ WT,
    u16* __restrict__ qb, u16* __restrict__ kb, u16* __restrict__ vT)
{
    __shared__ u16 la[128 * 64];
    __shared__ u16 lb[128 * 64];
    const int tid  = threadIdx.x;
    const int m0   = blockIdx.x * 128;
    const int w    = blockIdx.y;              // 0=q, 1=k, 2=v
    const int lane = tid & 63;
    const int wid  = tid >> 6;
    const int wr = wid >> 1, wc = wid & 1;
    const int lrow = lane & 15, lk = lane >> 4;
    const u16* wt = WT + ((size_t)w << 17);

    f32x4 acc[4][4];
#pragma unroll
    for (int i = 0; i < 4; ++i)
#pragma unroll
        for (int j = 0; j < 4; ++j) acc[i][j] = (f32x4){0.f, 0.f, 0.f, 0.f};

    for (int kt = 0; kt < 16; ++kt) {
        __syncthreads();
        // stage A: x f32 -> bf16 LDS  (128 rows x 64 k)
#pragma unroll
        for (int i = 0; i < 4; ++i) {
            int g = tid + i * 256;            // 0..1023
            int row = g >> 3, kg = g & 7;
            const float* src = x + (size_t)(m0 + row) * 1024 + kt * 64 + kg * 8;
            f32x4v f0 = *(const f32x4v*)src;
            f32x4v f1 = *(const f32x4v*)(src + 4);
            u16x8 v;
            v[0] = f2bf(f0[0]); v[1] = f2bf(f0[1]); v[2] = f2bf(f0[2]); v[3] = f2bf(f0[3]);
            v[4] = f2bf(f1[0]); v[5] = f2bf(f1[1]); v[6] = f2bf(f1[2]); v[7] = f2bf(f1[3]);
            *(u16x8*)(&la[row * 64 + ((kg ^ (row & 7)) << 3)]) = v;
        }
        // stage B: WT bf16 -> LDS (128 n-rows x 64 k)
#pragma unroll
        for (int i = 0; i < 4; ++i) {
            int g = tid + i * 256;
            int row = g >> 3, kg = g & 7;
            u16x8 v = *(const u16x8*)(wt + (size_t)row * 1024 + kt * 64 + kg * 8);
            *(u16x8*)(&lb[row * 64 + ((kg ^ (row & 7)) << 3)]) = v;
        }
        __syncthreads();
#pragma unroll
        for (int ks = 0; ks < 2; ++ks) {
            short8 af[4], bfr[4];
#pragma unroll
            for (int mf = 0; mf < 4; ++mf) {
                int row = wr * 64 + mf * 16 + lrow;
                int blk = (ks * 4 + lk) ^ (row & 7);
                af[mf] = *(const short8*)(&la[row * 64 + (blk << 3)]);
            }
#pragma unroll
            for (int nf = 0; nf < 4; ++nf) {
                int row = wc * 64 + nf * 16 + lrow;
                int blk = (ks * 4 + lk) ^ (row & 7);
                bfr[nf] = *(const short8*)(&lb[row * 64 + (blk << 3)]);
            }
#pragma unroll
            for (int mf = 0; mf < 4; ++mf)
#pragma unroll
                for (int nf = 0; nf < 4; ++nf)
                    acc[mf][nf] = MFMA16x16x32(af[mf], bfr[nf], acc[mf][nf], 0, 0, 0);
        }
    }
    // epilogue: C/D layout col=lane&15, row=(lane>>4)*4+jj
    if (w < 2) {
        u16* dst = (w == 0) ? qb : kb;
#pragma unroll
        for (int mf = 0; mf < 4; ++mf) {
            int row0 = m0 + wr * 64 + mf * 16 + lk * 4;
#pragma unroll
            for (int nf = 0; nf < 4; ++nf) {
                int col = wc * 64 + nf * 16 + lrow;
#pragma unroll
                for (int jj = 0; jj < 4; ++jj)
                    dst[(size_t)(row0 + jj) * 128 + col] = f2bf(acc[mf][nf][jj]);
            }
        }
    } else {
        // v: store transposed vT[b][d][t], 4 contiguous t per lane -> 8B stores
#pragma unroll
        for (int mf = 0; mf < 4; ++mf) {
            int row0 = m0 + wr * 64 + mf * 16 + lk * 4;
            int bb = row0 >> 11, t0 = row0 & 2047;
#pragma unroll
            for (int nf = 0; nf < 4; ++nf) {
                int col = wc * 64 + nf * 16 + lrow;
                u16x4 v;
#pragma unroll
                for (int jj = 0; jj < 4; ++jj) v[jj] = f2bf(acc[mf][nf][jj]);
                *(u16x4*)(&vT[((size_t)bb * 128 + col) * 2048 + t0]) = v;
            }
        }
    }
}

// ---------------------------------------------------------------------------
// Kernel 2: causal flash attention.  Grid (32 q-tiles, 8 batches), 4 waves.
// Each wave owns 16 q-rows; KV tile = 64.  Q in regs; K,V^T staged in swizzled
// LDS; P routed through per-wave private LDS region.
// ---------------------------------------------------------------------------
__global__ __launch_bounds__(256) void k_flash(
    const u16* __restrict__ qb, const u16* __restrict__ kb, const u16* __restrict__ vT,
    float* __restrict__ out)
{
    __shared__ u16 k_lds[64 * 128];
    __shared__ u16 v_lds[128 * 64];
    __shared__ u16 p_lds[4 * 16 * 64];
    const int tid  = threadIdx.x;
    const int lane = tid & 63, wid = tid >> 6;
    const int lrow = lane & 15, lk = lane >> 4;
    const int b = blockIdx.y, qt = blockIdx.x;

    // Q fragments (A-operand): row = lane&15, k = ks*32 + (lane>>4)*8 .. +7
    short8 qf[4];
    {
        const u16* qp = qb + ((size_t)b * 2048 + qt * 64 + wid * 16 + lrow) * 128;
#pragma unroll
        for (int ks = 0; ks < 4; ++ks)
            qf[ks] = *(const short8*)(qp + ks * 32 + lk * 8);
    }
    f32x4 of[8];
#pragma unroll
    for (int i = 0; i < 8; ++i) of[i] = (f32x4){0.f, 0.f, 0.f, 0.f};
    float mrun[4], lsum[4];
#pragma unroll
    for (int j = 0; j < 4; ++j) { mrun[j] = -1e30f; lsum[j] = 0.f; }

    u16* pw = p_lds + wid * (16 * 64);

    for (int kt = 0; kt <= qt; ++kt) {
        __syncthreads();
        // stage K tile: k_lds[kv 64][d 128], block(8 bf16) idx ^= row&7
#pragma unroll
        for (int i = 0; i < 4; ++i) {
            int g = tid + i * 256;
            int row = g >> 4, kg = g & 15;
            u16x8 v = *(const u16x8*)(kb + ((size_t)b * 2048 + kt * 64 + row) * 128 + kg * 8);
            *(u16x8*)(&k_lds[row * 128 + ((kg ^ (row & 7)) << 3)]) = v;
        }
        // stage V^T tile: v_lds[d 128][kv 64]
#pragma unroll
        for (int i = 0; i < 4; ++i) {
            int g = tid + i * 256;
            int row = g >> 3, kg = g & 7;
            u16x8 v = *(const u16x8*)(vT + ((size_t)b * 128 + row) * 2048 + kt * 64 + kg * 8);
            *(u16x8*)(&v_lds[row * 64 + ((kg ^ (row & 7)) << 3)]) = v;
        }
        __syncthreads();

        // S = Q K^T : 4 n-frags x 4 k-subtiles
        f32x4 sf[4];
#pragma unroll
        for (int nf = 0; nf < 4; ++nf) sf[nf] = (f32x4){0.f, 0.f, 0.f, 0.f};
#pragma unroll
        for (int ks = 0; ks < 4; ++ks)
#pragma unroll
            for (int nf = 0; nf < 4; ++nf) {
                int row = nf * 16 + lrow;
                int blk = (ks * 4 + lk) ^ (row & 7);
                short8 bfr = *(const short8*)(&k_lds[row * 128 + (blk << 3)]);
                sf[nf] = MFMA16x16x32(qf[ks], bfr, sf[nf], 0, 0, 0);
            }

        // scale + causal mask (only diagonal tile needs the mask)
        float p[4][4];
        const bool diag = (kt == qt);
#pragma unroll
        for (int nf = 0; nf < 4; ++nf)
#pragma unroll
            for (int jj = 0; jj < 4; ++jj) {
                float s = sf[nf][jj] * 0.03125f;  // C^-0.5 = 1/32 exactly
                if (diag && (nf * 16 + lrow > wid * 16 + lk * 4 + jj)) s = -1e30f;
                p[nf][jj] = s;
            }
        // online softmax: row stats live in lanes of the same 16-group
        float mt[4], rs[4], scold[4];
#pragma unroll
        for (int jj = 0; jj < 4; ++jj)
            mt[jj] = fmaxf(fmaxf(p[0][jj], p[1][jj]), fmaxf(p[2][jj], p[3][jj]));
#pragma unroll
        for (int off = 1; off < 16; off <<= 1)
#pragma unroll
            for (int jj = 0; jj < 4; ++jj)
                mt[jj] = fmaxf(mt[jj], __shfl_xor(mt[jj], off));
#pragma unroll
        for (int jj = 0; jj < 4; ++jj) {
            float mnew = fmaxf(mrun[jj], mt[jj]);
            scold[jj]  = __expf(mrun[jj] - mnew);
            mrun[jj]   = mnew;
            rs[jj]     = 0.f;
        }
#pragma unroll
        for (int nf = 0; nf < 4; ++nf)
#pragma unroll
            for (int jj = 0; jj < 4; ++jj) {
                float e = __expf(p[nf][jj] - mrun[jj]);
                p[nf][jj] = e;
                rs[jj] += e;
            }
#pragma unroll
        for (int off = 1; off < 16; off <<= 1)
#pragma unroll
            for (int jj = 0; jj < 4; ++jj)
                rs[jj] += __shfl_xor(rs[jj], off);
#pragma unroll
        for (int jj = 0; jj < 4; ++jj)
            lsum[jj] = lsum[jj] * scold[jj] + rs[jj];
#pragma unroll
        for (int df = 0; df < 8; ++df)
#pragma unroll
            for (int jj = 0; jj < 4; ++jj)
                of[df][jj] *= scold[jj];

        // P -> per-wave LDS (bf16, swizzled), then A-frags for PV
#pragma unroll
        for (int nf = 0; nf < 4; ++nf)
#pragma unroll
            for (int jj = 0; jj < 4; ++jj) {
                int row = lk * 4 + jj;
                int col = nf * 16 + lrow;
                pw[row * 64 + (((col >> 3) ^ (row & 7)) << 3) + (col & 7)] = f2bf(p[nf][jj]);
            }
        asm volatile("s_waitcnt lgkmcnt(0)" ::: "memory");
        __builtin_amdgcn_sched_barrier(0);

        short8 paf[2];
#pragma unroll
        for (int ks2 = 0; ks2 < 2; ++ks2) {
            int blk = (ks2 * 4 + lk) ^ (lrow & 7);
            paf[ks2] = *(const short8*)(&pw[lrow * 64 + (blk << 3)]);
        }
#pragma unroll
        for (int ks2 = 0; ks2 < 2; ++ks2)
#pragma unroll
            for (int df = 0; df < 8; ++df) {
                int row = df * 16 + lrow;
                int blk = (ks2 * 4 + lk) ^ (row & 7);
                short8 bfr = *(const short8*)(&v_lds[row * 64 + (blk << 3)]);
                of[df] = MFMA16x16x32(paf[ks2], bfr, of[df], 0, 0, 0);
            }
    }

    // epilogue: O / l
#pragma unroll
    for (int jj = 0; jj < 4; ++jj) lsum[jj] = 1.f / lsum[jj];
    float* op = out + ((size_t)b * 2048 + qt * 64 + wid * 16 + lk * 4) * 128;
#pragma unroll
    for (int df = 0; df < 8; ++df)
#pragma unroll
        for (int jj = 0; jj < 4; ++jj)
            op[(size_t)jj * 128 + df * 16 + lrow] = of[df][jj] * lsum[jj];
}

// ---------------------------------------------------------------------------
extern "C" void kernel_launch(void* const* d_in, const int* in_sizes, int n_in,
                              void* d_out, int out_size, void* d_ws, size_t ws_size,
                              hipStream_t stream) {
    const float* x  = (const float*)d_in[0];
    const float* Wq = (const float*)d_in[1];
    const float* Wk = (const float*)d_in[2];
    const float* Wv = (const float*)d_in[3];
    float* out = (float*)d_out;

    u16* ws = (u16*)d_ws;
    u16* qb = ws;                                  // [8*2048][128] bf16
    u16* kb = ws + (size_t)16384 * 128;            // [8*2048][128] bf16
    u16* vT = ws + (size_t)2 * 16384 * 128;        // [8][128][2048] bf16
    u16* WT = ws + (size_t)3 * 16384 * 128;        // [3][128][1024] bf16

    k_transpose_w<<<192, 256, 0, stream>>>(Wq, Wk, Wv, WT);
    k_qkv_gemm<<<dim3(128, 3), 256, 0, stream>>>(x, WT, qb, kb, vT);
    k_flash<<<dim3(32, 8), 256, 0, stream>>>(qb, kb, vT, out);
}